// Round 4
// baseline (1055.839 us; speedup 1.0000x reference)
//
#include <hip/hip_runtime.h>
#include <hip/hip_bf16.h>

#define EPSV 1e-5f
#define BKT 128            // nodes per bucket
#define NB  782            // ceil(100000/128)

__device__ inline void atomAddG(float* p, float v) { unsafeAtomicAdd(p, v); }

// ---------------- bucket histogram (LDS-aggregated) ----------------
__global__ __launch_bounds__(256) void bhist_kernel(
    const int* __restrict__ edges, int* __restrict__ gbcnt, int E)
{
    __shared__ int lh[NB];
    const int t = threadIdx.x;
    for (int i = t; i < NB; i += 256) lh[i] = 0;
    __syncthreads();
    const int base = blockIdx.x * 4096;
    #pragma unroll
    for (int i = 0; i < 16; ++i) {
        int e = base + i * 256 + t;
        if (e < E) atomicAdd(&lh[edges[E + e] >> 7], 1);
    }
    __syncthreads();
    for (int i = t; i < NB; i += 256) {
        int c = lh[i];
        if (c) atomicAdd(&gbcnt[i], c);
    }
}

// ------- bucket scan (single block): bbase exclusive + cursor copy -------
__global__ __launch_bounds__(256) void bscan_kernel(
    const int* __restrict__ gbcnt, int* __restrict__ bbase,
    int* __restrict__ gcursor, int E)
{
    __shared__ int l[256];
    const int t = threadIdx.x;
    int b0 = t * 4;
    int v0 = (b0 + 0 < NB) ? gbcnt[b0 + 0] : 0;
    int v1 = (b0 + 1 < NB) ? gbcnt[b0 + 1] : 0;
    int v2 = (b0 + 2 < NB) ? gbcnt[b0 + 2] : 0;
    int v3 = (b0 + 3 < NB) ? gbcnt[b0 + 3] : 0;
    int tot = v0 + v1 + v2 + v3;
    l[t] = tot;
    __syncthreads();
    for (int o = 1; o < 256; o <<= 1) {
        int add = (t >= o) ? l[t - o] : 0;
        __syncthreads();
        l[t] += add;
        __syncthreads();
    }
    int off = l[t] - tot;
    if (b0 + 0 < NB) { bbase[b0 + 0] = off;                gcursor[b0 + 0] = off; }
    if (b0 + 1 < NB) { bbase[b0 + 1] = off + v0;           gcursor[b0 + 1] = off + v0; }
    if (b0 + 2 < NB) { bbase[b0 + 2] = off + v0 + v1;      gcursor[b0 + 2] = off + v0 + v1; }
    if (b0 + 3 < NB) { bbase[b0 + 3] = off + v0 + v1 + v2; gcursor[b0 + 3] = off + v0 + v1 + v2; }
    if (t == 0) bbase[NB] = E;
}

// ------- bucket fill: pk = (src<<7)|(dst&127), grouped by bucket -------
__global__ __launch_bounds__(256) void bfill_kernel(
    const int* __restrict__ edges, int* __restrict__ gcursor,
    int* __restrict__ pk, int E)
{
    __shared__ int lh[NB];
    __shared__ int lbase[NB];
    const int t = threadIdx.x;
    for (int i = t; i < NB; i += 256) lh[i] = 0;
    __syncthreads();
    const int base = blockIdx.x * 4096;
    int dv[16];
    #pragma unroll
    for (int i = 0; i < 16; ++i) {
        int e = base + i * 256 + t;
        dv[i] = (e < E) ? edges[E + e] : -1;
        if (dv[i] >= 0) atomicAdd(&lh[dv[i] >> 7], 1);
    }
    __syncthreads();
    for (int i = t; i < NB; i += 256) {
        int c = lh[i];
        lbase[i] = c ? atomicAdd(&gcursor[i], c) : 0;
        lh[i] = 0;
    }
    __syncthreads();
    #pragma unroll
    for (int i = 0; i < 16; ++i) {
        int e = base + i * 256 + t;
        if (dv[i] >= 0) {
            int s = edges[e];
            int b = dv[i] >> 7;
            int pos = lbase[b] + atomicAdd(&lh[b], 1);
            pk[pos] = (s << 7) | (dv[i] & 127);
        }
    }
}

// ------- graph boundaries from sorted membership: gstart[g], g=0..64 -------
__global__ __launch_bounds__(256) void bounds_kernel(
    const int* __restrict__ membership, int* __restrict__ gstart, int N)
{
    int n = blockIdx.x * 256 + threadIdx.x;
    if (n > N) return;
    int mp = (n == 0) ? -1 : membership[n - 1];
    int mc = (n == N) ? 64 : membership[n];
    for (int g = mp + 1; g <= mc; ++g) gstart[g] = n;
}

// ---- layer 1 fused: LDS scatter of x + dense 3->64 + relu + BN1 stats ----
__global__ __launch_bounds__(256) void layer1_kernel(
    const float* __restrict__ x, const int* __restrict__ bbase,
    const int* __restrict__ pk,
    const float* __restrict__ W_rel1, const float* __restrict__ b_rel1,
    const float* __restrict__ W_root1,
    float* __restrict__ u1, float* __restrict__ sums, float* __restrict__ sumsq,
    int N)
{
    __shared__ __align__(16) float accx[BKT * 4];
    __shared__ float red[4][64];
    const int t = threadIdx.x;
    for (int i = t; i < BKT * 4; i += 256) accx[i] = 0.f;
    __syncthreads();
    const int e0 = bbase[blockIdx.x], e1 = bbase[blockIdx.x + 1];
    for (int e = e0 + t; e < e1; e += 256) {
        int v = pk[e];
        int s = v >> 7, ld = v & 127;
        float x0 = x[s * 3 + 0], x1 = x[s * 3 + 1], x2 = x[s * 3 + 2];
        atomicAdd(&accx[ld * 4 + 0], x0);
        atomicAdd(&accx[ld * 4 + 1], x1);
        atomicAdd(&accx[ld * 4 + 2], x2);
    }
    __syncthreads();
    const int f = t & 63, r4 = t >> 6;
    const float wr0 = W_rel1[f], wr1 = W_rel1[64 + f], wr2 = W_rel1[128 + f];
    const float wo0 = W_root1[f], wo1 = W_root1[64 + f], wo2 = W_root1[128 + f];
    const float bb = b_rel1[f];
    const int n0 = blockIdx.x * BKT;
    float ps = 0.f, pq = 0.f;
    for (int i = 0; i < BKT / 4; ++i) {
        int nl = i * 4 + r4;
        int n = n0 + nl;
        if (n < N) {
            float a0 = accx[nl * 4 + 0], a1 = accx[nl * 4 + 1], a2 = accx[nl * 4 + 2];
            float x0 = x[n * 3 + 0], x1 = x[n * 3 + 1], x2 = x[n * 3 + 2];
            float v = bb;
            v = fmaf(a0, wr0, v); v = fmaf(a1, wr1, v); v = fmaf(a2, wr2, v);
            v = fmaf(x0, wo0, v); v = fmaf(x1, wo1, v); v = fmaf(x2, wo2, v);
            v = fmaxf(v, 0.f);
            u1[n * 64 + f] = v;
            ps += v; pq += v * v;
        }
    }
    red[r4][f] = ps; __syncthreads();
    if (r4 == 0) atomAddG(&sums[f], red[0][f] + red[1][f] + red[2][f] + red[3][f]);
    __syncthreads();
    red[r4][f] = pq; __syncthreads();
    if (r4 == 0) atomAddG(&sumsq[f], red[0][f] + red[1][f] + red[2][f] + red[3][f]);
}

// ------------- BN: scale = g*rsqrt(var+eps), shift = b - mean*scale -------------
__global__ void bnscale_kernel(const float* __restrict__ sums, const float* __restrict__ sumsq,
                               const float* __restrict__ g, const float* __restrict__ b,
                               float invn, int C,
                               float* __restrict__ scale, float* __restrict__ shift)
{
    int f = blockIdx.x * blockDim.x + threadIdx.x;
    if (f >= C) return;
    float m = sums[f] * invn;
    float v = sumsq[f] * invn - m * m;
    float sc = g[f] * rsqrtf(v + EPSV);
    scale[f] = sc;
    shift[f] = b[f] - m * sc;
}

// ---- layer 2 fused: LDS scatter of u1 rows -> algebraic BN1 -> dual dense
// ---- (reg weights) -> relu -> BN2 stats -> pooled. Block = 128-node bucket. ----
__global__ __launch_bounds__(256) void layer2_kernel(
    const float* __restrict__ u1, const int* __restrict__ bbase,
    const int* __restrict__ pk, const int* __restrict__ membership,
    const float* __restrict__ scale1, const float* __restrict__ shift1,
    const float* __restrict__ W_rel2, const float* __restrict__ b_rel2,
    const float* __restrict__ W_root2,
    float* __restrict__ pooled, float* __restrict__ sums, float* __restrict__ sumsq,
    int N)
{
    __shared__ __align__(16) float acc[BKT * 64];   // 32 KB
    __shared__ __align__(16) float rowH[4][64];
    __shared__ float cntl[BKT];
    __shared__ float red[4][64];
    const int t = threadIdx.x;
    const int f = t & 63, w = t >> 6;
    for (int i = t; i < BKT * 64; i += 256) acc[i] = 0.f;
    for (int i = t; i < BKT; i += 256) cntl[i] = 0.f;
    __syncthreads();

    const int e0 = bbase[blockIdx.x], e1 = bbase[blockIdx.x + 1];
    // scatter u1 rows: wave-per-edge, 8-deep pipeline
    for (int base = e0 + w * 8; base < e1; base += 32) {
        int m = e1 - base; if (m > 8) m = 8;
        if (m == 8) {
            int v0 = pk[base + 0], v1 = pk[base + 1], v2 = pk[base + 2], v3 = pk[base + 3];
            int v4 = pk[base + 4], v5 = pk[base + 5], v6 = pk[base + 6], v7 = pk[base + 7];
            float a0 = u1[(v0 >> 7) * 64 + f];
            float a1 = u1[(v1 >> 7) * 64 + f];
            float a2 = u1[(v2 >> 7) * 64 + f];
            float a3 = u1[(v3 >> 7) * 64 + f];
            float a4 = u1[(v4 >> 7) * 64 + f];
            float a5 = u1[(v5 >> 7) * 64 + f];
            float a6 = u1[(v6 >> 7) * 64 + f];
            float a7 = u1[(v7 >> 7) * 64 + f];
            atomicAdd(&acc[(v0 & 127) * 64 + f], a0);
            atomicAdd(&acc[(v1 & 127) * 64 + f], a1);
            atomicAdd(&acc[(v2 & 127) * 64 + f], a2);
            atomicAdd(&acc[(v3 & 127) * 64 + f], a3);
            atomicAdd(&acc[(v4 & 127) * 64 + f], a4);
            atomicAdd(&acc[(v5 & 127) * 64 + f], a5);
            atomicAdd(&acc[(v6 & 127) * 64 + f], a6);
            atomicAdd(&acc[(v7 & 127) * 64 + f], a7);
            if (f == 0) {
                atomicAdd(&cntl[v0 & 127], 1.f);
                atomicAdd(&cntl[v1 & 127], 1.f);
                atomicAdd(&cntl[v2 & 127], 1.f);
                atomicAdd(&cntl[v3 & 127], 1.f);
                atomicAdd(&cntl[v4 & 127], 1.f);
                atomicAdd(&cntl[v5 & 127], 1.f);
                atomicAdd(&cntl[v6 & 127], 1.f);
                atomicAdd(&cntl[v7 & 127], 1.f);
            }
        } else {
            for (int i = 0; i < m; ++i) {
                int v = pk[base + i];
                atomicAdd(&acc[(v & 127) * 64 + f], u1[(v >> 7) * 64 + f]);
                if (f == 0) atomicAdd(&cntl[v & 127], 1.f);
            }
        }
    }
    __syncthreads();

    // algebraic BN1 on aggregate: acc = scale1[k]*acc + cnt*shift1[k]
    for (int i = t; i < BKT * 64; i += 256) {
        int k = i & 63, nl = i >> 6;
        acc[i] = fmaf(acc[i], scale1[k], cntl[nl] * shift1[k]);
    }
    __syncthreads();

    // finish: per-node dual dense with register weight columns
    float wrel[64], wroot[64];
    #pragma unroll
    for (int k = 0; k < 64; ++k) wrel[k] = W_rel2[k * 64 + f];
    #pragma unroll
    for (int k = 0; k < 64; ++k) wroot[k] = W_root2[k * 64 + f];
    const float sc1 = scale1[f], sh1 = shift1[f], bb = b_rel2[f];
    const int n0 = blockIdx.x * BKT;
    float ps = 0.f, pq = 0.f, pacc = 0.f;
    int curg = -1;
    for (int j = 0; j < BKT / 4; ++j) {
        int nl = w * (BKT / 4) + j;
        int n = n0 + nl;
        if (n >= N) break;
        rowH[w][f] = fmaf(u1[n * 64 + f], sc1, sh1);
        __builtin_amdgcn_wave_barrier();
        float o0 = bb, o1 = 0.f, o2 = 0.f, o3 = 0.f;
        #pragma unroll
        for (int k4 = 0; k4 < 16; ++k4) {
            float4 h = *(const float4*)&rowH[w][k4 * 4];
            float4 a = *(const float4*)&acc[nl * 64 + k4 * 4];
            o0 = fmaf(h.x, wroot[k4 * 4 + 0], fmaf(a.x, wrel[k4 * 4 + 0], o0));
            o1 = fmaf(h.y, wroot[k4 * 4 + 1], fmaf(a.y, wrel[k4 * 4 + 1], o1));
            o2 = fmaf(h.z, wroot[k4 * 4 + 2], fmaf(a.z, wrel[k4 * 4 + 2], o2));
            o3 = fmaf(h.w, wroot[k4 * 4 + 3], fmaf(a.w, wrel[k4 * 4 + 3], o3));
        }
        __builtin_amdgcn_wave_barrier();
        float o = fmaxf((o0 + o1) + (o2 + o3), 0.f);
        ps += o; pq += o * o;
        int g = membership[n];
        if (g != curg) {
            if (curg >= 0) atomAddG(&pooled[curg * 64 + f], pacc);
            pacc = 0.f; curg = g;
        }
        pacc += o;
    }
    if (curg >= 0) atomAddG(&pooled[curg * 64 + f], pacc);

    red[w][f] = ps; __syncthreads();
    if (w == 0) atomAddG(&sums[f], red[0][f] + red[1][f] + red[2][f] + red[3][f]);
    __syncthreads();
    red[w][f] = pq; __syncthreads();
    if (w == 0) atomAddG(&sumsq[f], red[0][f] + red[1][f] + red[2][f] + red[3][f]);
}

// ---- head part 1: pm = BN2(pooled/cnt); z = BN3(relu(pm@W_fc1+b_fc1)) ----
__global__ __launch_bounds__(1024) void fc1_kernel(
    const float* __restrict__ pooled, const int* __restrict__ gstart,
    const float* __restrict__ scale2, const float* __restrict__ shift2,
    const float* __restrict__ W_fc1, const float* __restrict__ b_fc1,
    const float* __restrict__ g3, const float* __restrict__ b3,
    float* __restrict__ z)
{
    __shared__ float pm[4096];
    __shared__ float reds[4][256], redq[4][256];
    __shared__ float lsc[256], lsh[256];
    const int t = threadIdx.x;
    for (int i = t; i < 4096; i += 1024) {
        int g = i >> 6, f = i & 63;
        float c = fmaxf((float)(gstart[g + 1] - gstart[g]), 1.0f);
        pm[i] = fmaf(pooled[i] / c, scale2[f], shift2[f]);
    }
    __syncthreads();
    const int col = t & 255, grp = t >> 8;
    float acc[16];
    const float bc = b_fc1[col];
    #pragma unroll
    for (int g = 0; g < 16; ++g) acc[g] = bc;
    for (int k = 0; k < 64; ++k) {
        float wv = W_fc1[k * 256 + col];
        #pragma unroll
        for (int g = 0; g < 16; ++g)
            acc[g] = fmaf(pm[(grp * 16 + g) * 64 + k], wv, acc[g]);
    }
    float s = 0.f, q = 0.f;
    #pragma unroll
    for (int g = 0; g < 16; ++g) {
        acc[g] = fmaxf(acc[g], 0.f);
        s += acc[g]; q += acc[g] * acc[g];
    }
    reds[grp][col] = s; redq[grp][col] = q;
    __syncthreads();
    if (grp == 0) {
        float S = reds[0][col] + reds[1][col] + reds[2][col] + reds[3][col];
        float Q = redq[0][col] + redq[1][col] + redq[2][col] + redq[3][col];
        float m = S * (1.0f / 64.0f);
        float v = Q * (1.0f / 64.0f) - m * m;
        float sc = g3[col] * rsqrtf(v + EPSV);
        lsc[col] = sc;
        lsh[col] = b3[col] - m * sc;
    }
    __syncthreads();
    float sc = lsc[col], sh = lsh[col];
    #pragma unroll
    for (int g = 0; g < 16; ++g)
        z[(grp * 16 + g) * 256 + col] = fmaf(acc[g], sc, sh);
}

// ---------------- head part 2: out = z @ W_fc2 + b_fc2, (64 x 10) ----------------
__global__ __launch_bounds__(640) void fc2_kernel(
    const float* __restrict__ z, const float* __restrict__ W_fc2,
    const float* __restrict__ b_fc2, float* __restrict__ out)
{
    int t = threadIdx.x;
    int g = t / 10, o = t % 10;
    float acc = b_fc2[o];
    for (int c = 0; c < 256; ++c)
        acc = fmaf(z[g * 256 + c], W_fc2[c * 10 + o], acc);
    out[g * 10 + o] = acc;
}

extern "C" void kernel_launch(void* const* d_in, const int* in_sizes, int n_in,
                              void* d_out, int out_size, void* d_ws, size_t ws_size,
                              hipStream_t stream) {
    const int N = 100000, E = 1600000;

    const float* x          = (const float*)d_in[0];
    const int*   membership = (const int*)d_in[1];
    const int*   edges      = (const int*)d_in[2];
    const float* W_rel1     = (const float*)d_in[3];
    const float* b_rel1     = (const float*)d_in[4];
    const float* W_root1    = (const float*)d_in[5];
    const float* W_rel2     = (const float*)d_in[6];
    const float* b_rel2     = (const float*)d_in[7];
    const float* W_root2    = (const float*)d_in[8];
    const float* g1         = (const float*)d_in[9];
    const float* b1         = (const float*)d_in[10];
    const float* g2         = (const float*)d_in[11];
    const float* b2         = (const float*)d_in[12];
    const float* W_fc1      = (const float*)d_in[13];
    const float* b_fc1      = (const float*)d_in[14];
    const float* g3         = (const float*)d_in[15];
    const float* b3         = (const float*)d_in[16];
    const float* W_fc2      = (const float*)d_in[17];
    const float* b_fc2      = (const float*)d_in[18];

    // workspace layout (4B elements)
    int*   wsi      = (int*)d_ws;
    float* wsf      = (float*)d_ws;
    int*   gbcnt    = wsi + 0;        // 784
    float* stats    = wsf + 784;      // 512
    float* pooled   = wsf + 1296;     // 4096
    int*   bbase    = wsi + 5392;     // 800 (NB+1)
    int*   gcursor  = wsi + 6192;     // 784
    int*   gstart   = wsi + 6976;     // 128
    int*   pk       = wsi + 7168;     // 1600000
    float* u1       = wsf + 1607168;  // 6400000
    float* z        = wsf + 8007168;  // 16384

    float* sums1  = stats + 0;
    float* sumsq1 = stats + 64;
    float* sums2  = stats + 128;
    float* sumsq2 = stats + 192;
    float* scale1 = stats + 256;
    float* shift1 = stats + 320;
    float* scale2 = stats + 384;
    float* shift2 = stats + 448;

    // zero gbcnt | stats | pooled (contiguous prefix, 21.6 KB)
    hipMemsetAsync(d_ws, 0, (size_t)(784 + 512 + 4096) * 4, stream);

    // bucket build (grouping only, no per-node sort)
    const int EB = (E + 4095) / 4096;  // 391
    bhist_kernel<<<EB, 256, 0, stream>>>(edges, gbcnt, E);
    bscan_kernel<<<1, 256, 0, stream>>>(gbcnt, bbase, gcursor, E);
    bfill_kernel<<<EB, 256, 0, stream>>>(edges, gcursor, pk, E);
    bounds_kernel<<<(N + 256) / 256, 256, 0, stream>>>(membership, gstart, N);

    // layer 1 (fused scatter + dense + stats)
    layer1_kernel<<<NB, 256, 0, stream>>>(
        x, bbase, pk, W_rel1, b_rel1, W_root1, u1, sums1, sumsq1, N);
    bnscale_kernel<<<1, 64, 0, stream>>>(sums1, sumsq1, g1, b1, 1.0f / N, 64, scale1, shift1);

    // layer 2 (fused scatter + BN1 + dense + relu + stats + pool)
    layer2_kernel<<<NB, 256, 0, stream>>>(
        u1, bbase, pk, membership, scale1, shift1,
        W_rel2, b_rel2, W_root2, pooled, sums2, sumsq2, N);
    bnscale_kernel<<<1, 64, 0, stream>>>(sums2, sumsq2, g2, b2, 1.0f / N, 64, scale2, shift2);

    // head
    fc1_kernel<<<1, 1024, 0, stream>>>(pooled, gstart, scale2, shift2,
                                       W_fc1, b_fc1, g3, b3, z);
    fc2_kernel<<<1, 640, 0, stream>>>(z, W_fc2, b_fc2, (float*)d_out);
}

// Round 5
// 323.924 us; speedup vs baseline: 3.2595x; 3.2595x over previous
//
#include <hip/hip_runtime.h>
#include <hip/hip_bf16.h>

#define EPSV 1e-5f
#define BKT 128            // nodes per bucket
#define NB  782            // ceil(100000/128)

__device__ inline void atomAddG(float* p, float v) { unsafeAtomicAdd(p, v); }

// ---------------- bucket histogram (LDS-aggregated) ----------------
__global__ __launch_bounds__(256) void bhist_kernel(
    const int* __restrict__ edges, int* __restrict__ gbcnt, int E)
{
    __shared__ int lh[NB];
    const int t = threadIdx.x;
    for (int i = t; i < NB; i += 256) lh[i] = 0;
    __syncthreads();
    const int base = blockIdx.x * 4096;
    #pragma unroll
    for (int i = 0; i < 16; ++i) {
        int e = base + i * 256 + t;
        if (e < E) atomicAdd(&lh[edges[E + e] >> 7], 1);
    }
    __syncthreads();
    for (int i = t; i < NB; i += 256) {
        int c = lh[i];
        if (c) atomicAdd(&gbcnt[i], c);
    }
}

// ------- bucket scan (single block): bbase exclusive + cursor copy -------
__global__ __launch_bounds__(256) void bscan_kernel(
    const int* __restrict__ gbcnt, int* __restrict__ bbase,
    int* __restrict__ gcursor, int E)
{
    __shared__ int l[256];
    const int t = threadIdx.x;
    int b0 = t * 4;
    int v0 = (b0 + 0 < NB) ? gbcnt[b0 + 0] : 0;
    int v1 = (b0 + 1 < NB) ? gbcnt[b0 + 1] : 0;
    int v2 = (b0 + 2 < NB) ? gbcnt[b0 + 2] : 0;
    int v3 = (b0 + 3 < NB) ? gbcnt[b0 + 3] : 0;
    int tot = v0 + v1 + v2 + v3;
    l[t] = tot;
    __syncthreads();
    for (int o = 1; o < 256; o <<= 1) {
        int add = (t >= o) ? l[t - o] : 0;
        __syncthreads();
        l[t] += add;
        __syncthreads();
    }
    int off = l[t] - tot;
    if (b0 + 0 < NB) { bbase[b0 + 0] = off;                gcursor[b0 + 0] = off; }
    if (b0 + 1 < NB) { bbase[b0 + 1] = off + v0;           gcursor[b0 + 1] = off + v0; }
    if (b0 + 2 < NB) { bbase[b0 + 2] = off + v0 + v1;      gcursor[b0 + 2] = off + v0 + v1; }
    if (b0 + 3 < NB) { bbase[b0 + 3] = off + v0 + v1 + v2; gcursor[b0 + 3] = off + v0 + v1 + v2; }
    if (t == 0) bbase[NB] = E;
}

// ------- bucket fill: pk = (src<<7)|(dst&127), grouped by bucket -------
__global__ __launch_bounds__(256) void bfill_kernel(
    const int* __restrict__ edges, int* __restrict__ gcursor,
    int* __restrict__ pk, int E)
{
    __shared__ int lh[NB];
    __shared__ int lbase[NB];
    const int t = threadIdx.x;
    for (int i = t; i < NB; i += 256) lh[i] = 0;
    __syncthreads();
    const int base = blockIdx.x * 4096;
    int dv[16];
    #pragma unroll
    for (int i = 0; i < 16; ++i) {
        int e = base + i * 256 + t;
        dv[i] = (e < E) ? edges[E + e] : -1;
        if (dv[i] >= 0) atomicAdd(&lh[dv[i] >> 7], 1);
    }
    __syncthreads();
    for (int i = t; i < NB; i += 256) {
        int c = lh[i];
        lbase[i] = c ? atomicAdd(&gcursor[i], c) : 0;
        lh[i] = 0;
    }
    __syncthreads();
    #pragma unroll
    for (int i = 0; i < 16; ++i) {
        int e = base + i * 256 + t;
        if (dv[i] >= 0) {
            int s = edges[e];
            int b = dv[i] >> 7;
            int pos = lbase[b] + atomicAdd(&lh[b], 1);
            pk[pos] = (s << 7) | (dv[i] & 127);
        }
    }
}

// ---- per-bucket fine sort: CSR rowstart + srcs, writes confined to 8KB window ----
__global__ __launch_bounds__(256) void bsort_kernel(
    const int* __restrict__ pk, const int* __restrict__ bbase,
    int* __restrict__ rowstart, int* __restrict__ srcs, int N, int E)
{
    __shared__ int lcnt[BKT];
    __shared__ int lscan[BKT];
    const int t = threadIdx.x;
    const int b = blockIdx.x;
    const int e0 = bbase[b], e1 = bbase[b + 1];
    if (t < BKT) lcnt[t] = 0;
    __syncthreads();
    for (int e = e0 + t; e < e1; e += 256) atomicAdd(&lcnt[pk[e] & 127], 1);
    __syncthreads();
    if (t < BKT) lscan[t] = lcnt[t];
    __syncthreads();
    for (int o = 1; o < BKT; o <<= 1) {
        int add = (t < BKT && t >= o) ? lscan[t - o] : 0;
        __syncthreads();
        if (t < BKT) lscan[t] += add;
        __syncthreads();
    }
    const int n0 = b * BKT;
    if (t < BKT) {
        int excl = lscan[t] - lcnt[t];
        lscan[t] = excl;                 // per-local-dst base offset
        int n = n0 + t;
        if (n <= N) rowstart[n] = e0 + excl;   // last bucket's t=32 writes rowstart[N]=E
        lcnt[t] = 0;                     // reuse as cursor
    }
    __syncthreads();
    for (int e = e0 + t; e < e1; e += 256) {
        int v = pk[e];
        int ld = v & 127;
        int pos = atomicAdd(&lcnt[ld], 1);
        srcs[e0 + lscan[ld] + pos] = v >> 7;
    }
}

// ------- graph boundaries from sorted membership: gstart[g] for g=0..64 -------
__global__ __launch_bounds__(256) void bounds_kernel(
    const int* __restrict__ membership, int* __restrict__ gstart, int N)
{
    int n = blockIdx.x * 256 + threadIdx.x;
    if (n > N) return;
    int mp = (n == 0) ? -1 : membership[n - 1];
    int mc = (n == N) ? 64 : membership[n];
    for (int g = mp + 1; g <= mc; ++g) gstart[g] = n;
}

// ---------------- gather layer 1: agg1[n] = sum x[srcs], IN=3, thread/node ----------------
__global__ __launch_bounds__(256) void gather1_kernel(
    const float* __restrict__ x, const int* __restrict__ rowstart,
    const int* __restrict__ srcs, float* __restrict__ agg1, int N)
{
    int n = blockIdx.x * 256 + threadIdx.x;
    if (n >= N) return;
    int s0 = rowstart[n], s1 = rowstart[n + 1];
    float a0 = 0.f, a1 = 0.f, a2 = 0.f;
    for (int j = s0; j < s1; ++j) {
        int s = srcs[j];
        a0 += x[s * 3 + 0];
        a1 += x[s * 3 + 1];
        a2 += x[s * 3 + 2];
    }
    agg1[n * 3 + 0] = a0;
    agg1[n * 3 + 1] = a1;
    agg1[n * 3 + 2] = a2;
}

// ------- layer 1 dense: u1 = relu(agg1@W_rel1 + b_rel1 + x@W_root1); stats -------
__global__ __launch_bounds__(256) void layer1_kernel(
    const float* __restrict__ x, const float* __restrict__ agg1,
    const float* __restrict__ W_rel1, const float* __restrict__ b_rel1,
    const float* __restrict__ W_root1,
    float* __restrict__ u1, float* __restrict__ sums, float* __restrict__ sumsq,
    int N)
{
    const int t = threadIdx.x;
    const int f = t & 63, r4 = t >> 6;
    const float wr0 = W_rel1[f], wr1 = W_rel1[64 + f], wr2 = W_rel1[128 + f];
    const float wo0 = W_root1[f], wo1 = W_root1[64 + f], wo2 = W_root1[128 + f];
    const float bb = b_rel1[f];
    float ps = 0.f, pq = 0.f;
    const int base = blockIdx.x * 128;
    for (int i = r4; i < 128; i += 4) {
        int n = base + i;
        if (n >= N) break;
        float a0 = agg1[n * 3 + 0], a1 = agg1[n * 3 + 1], a2 = agg1[n * 3 + 2];
        float x0 = x[n * 3 + 0], x1 = x[n * 3 + 1], x2 = x[n * 3 + 2];
        float v = bb;
        v = fmaf(a0, wr0, v); v = fmaf(a1, wr1, v); v = fmaf(a2, wr2, v);
        v = fmaf(x0, wo0, v); v = fmaf(x1, wo1, v); v = fmaf(x2, wo2, v);
        v = fmaxf(v, 0.f);
        u1[n * 64 + f] = v;
        ps += v; pq += v * v;
    }
    __shared__ float lsum[4][64], lsq[4][64];
    lsum[r4][f] = ps; lsq[r4][f] = pq;
    __syncthreads();
    if (r4 == 0) {
        float s = lsum[0][f] + lsum[1][f] + lsum[2][f] + lsum[3][f];
        float q = lsq[0][f] + lsq[1][f] + lsq[2][f] + lsq[3][f];
        atomAddG(&sums[f], s);
        atomAddG(&sumsq[f], q);
    }
}

// ------------- BN: scale = g*rsqrt(var+eps), shift = b - mean*scale -------------
__global__ void bnscale_kernel(const float* __restrict__ sums, const float* __restrict__ sumsq,
                               const float* __restrict__ g, const float* __restrict__ b,
                               float invn, int C,
                               float* __restrict__ scale, float* __restrict__ shift)
{
    int f = blockIdx.x * blockDim.x + threadIdx.x;
    if (f >= C) return;
    float m = sums[f] * invn;
    float v = sumsq[f] * invn - m * m;
    float sc = g[f] * rsqrtf(v + EPSV);
    scale[f] = sc;
    shift[f] = b[f] - m * sc;
}

// ---- transform: h1 = BN1(u1); t[n] = h1@W_rel2 (IN-PLACE over u1);
// ----            p[n] = h1@W_root2 + b_rel2. Dense, LDS-staged rows. ----
__global__ __launch_bounds__(256) void transform_kernel(
    float* __restrict__ u1t,                 // read u1, write t in-place
    float* __restrict__ p,
    const float* __restrict__ scale1, const float* __restrict__ shift1,
    const float* __restrict__ W_rel2, const float* __restrict__ b_rel2,
    const float* __restrict__ W_root2, int N)
{
    __shared__ float lWrel[4096];
    __shared__ float lWroot[4096];
    __shared__ float rowH[4][64];
    const int t = threadIdx.x;
    const int f = t & 63, r4 = t >> 6;
    for (int i = t; i < 4096; i += 256) {
        lWrel[i] = W_rel2[i];
        lWroot[i] = W_root2[i];
    }
    __syncthreads();
    const float sc1 = scale1[f], sh1 = shift1[f], bb = b_rel2[f];
    const int base = blockIdx.x * 64;
    for (int i = 0; i < 16; ++i) {
        int n = base + i * 4 + r4;
        bool ok = (n < N);
        if (ok) rowH[r4][f] = fmaf(u1t[n * 64 + f], sc1, sh1);
        __syncthreads();
        if (ok) {
            float o1 = 0.f, o2 = bb;
            #pragma unroll
            for (int k = 0; k < 64; ++k) {
                float h = rowH[r4][k];
                o1 = fmaf(h, lWrel[k * 64 + f], o1);
                o2 = fmaf(h, lWroot[k * 64 + f], o2);
            }
            u1t[n * 64 + f] = o1;
            p[n * 64 + f] = o2;
        }
        __syncthreads();
    }
}

// ---- gather+pool: u2[n] = relu(sum_src t[src] + p[n]); BN2 stats; pooled sums.
// ---- Wave per node-chunk, lane = feature, 8-deep load pipeline, no big LDS. ----
__global__ __launch_bounds__(256, 8) void gatherpool_kernel(
    const float* __restrict__ t, const float* __restrict__ p,
    const int* __restrict__ rowstart, const int* __restrict__ srcs,
    const int* __restrict__ membership,
    float* __restrict__ pooled, float* __restrict__ sums, float* __restrict__ sumsq,
    int N, int chunk)
{
    __shared__ float red[4][64];
    const int tid = threadIdx.x;
    const int w = tid >> 6, f = tid & 63;
    const int gw = __builtin_amdgcn_readfirstlane(blockIdx.x * 4 + w);
    const int n0 = gw * chunk;
    const int n1 = min(N, n0 + chunk);
    float ps = 0.f, pq = 0.f, pacc = 0.f;
    int curg = (n0 < N) ? membership[n0] : -1;

    for (int n = n0; n < n1; ++n) {
        int s0 = rowstart[n], s1 = rowstart[n + 1];
        float acc = p[n * 64 + f];
        int j = s0;
        for (; j + 7 < s1; j += 8) {
            int i0 = srcs[j] * 64 + f, i1 = srcs[j + 1] * 64 + f;
            int i2 = srcs[j + 2] * 64 + f, i3 = srcs[j + 3] * 64 + f;
            int i4 = srcs[j + 4] * 64 + f, i5 = srcs[j + 5] * 64 + f;
            int i6 = srcs[j + 6] * 64 + f, i7 = srcs[j + 7] * 64 + f;
            float v0 = t[i0], v1 = t[i1], v2 = t[i2], v3 = t[i3];
            float v4 = t[i4], v5 = t[i5], v6 = t[i6], v7 = t[i7];
            acc += ((v0 + v1) + (v2 + v3)) + ((v4 + v5) + (v6 + v7));
        }
        for (; j < s1; ++j) acc += t[srcs[j] * 64 + f];

        acc = fmaxf(acc, 0.f);
        ps += acc; pq += acc * acc;

        int g = membership[n];
        if (g != curg) {
            atomAddG(&pooled[curg * 64 + f], pacc);
            pacc = 0.f;
            curg = g;
        }
        pacc += acc;
    }
    if (curg >= 0) atomAddG(&pooled[curg * 64 + f], pacc);

    red[w][f] = ps;
    __syncthreads();
    if (w == 0) atomAddG(&sums[f], red[0][f] + red[1][f] + red[2][f] + red[3][f]);
    __syncthreads();
    red[w][f] = pq;
    __syncthreads();
    if (w == 0) atomAddG(&sumsq[f], red[0][f] + red[1][f] + red[2][f] + red[3][f]);
}

// ---- head part 1: pm = BN2(pooled/cnt); z = BN3(relu(pm@W_fc1+b_fc1)) ----
__global__ __launch_bounds__(1024) void fc1_kernel(
    const float* __restrict__ pooled, const int* __restrict__ gstart,
    const float* __restrict__ scale2, const float* __restrict__ shift2,
    const float* __restrict__ W_fc1, const float* __restrict__ b_fc1,
    const float* __restrict__ g3, const float* __restrict__ b3,
    float* __restrict__ z)
{
    __shared__ float pm[4096];
    __shared__ float reds[4][256], redq[4][256];
    __shared__ float lsc[256], lsh[256];
    const int t = threadIdx.x;
    for (int i = t; i < 4096; i += 1024) {
        int g = i >> 6, f = i & 63;
        float c = fmaxf((float)(gstart[g + 1] - gstart[g]), 1.0f);
        pm[i] = fmaf(pooled[i] / c, scale2[f], shift2[f]);
    }
    __syncthreads();
    const int col = t & 255, grp = t >> 8;
    float acc[16];
    const float bc = b_fc1[col];
    #pragma unroll
    for (int g = 0; g < 16; ++g) acc[g] = bc;
    for (int k = 0; k < 64; ++k) {
        float wv = W_fc1[k * 256 + col];
        #pragma unroll
        for (int g = 0; g < 16; ++g)
            acc[g] = fmaf(pm[(grp * 16 + g) * 64 + k], wv, acc[g]);
    }
    float s = 0.f, q = 0.f;
    #pragma unroll
    for (int g = 0; g < 16; ++g) {
        acc[g] = fmaxf(acc[g], 0.f);
        s += acc[g]; q += acc[g] * acc[g];
    }
    reds[grp][col] = s; redq[grp][col] = q;
    __syncthreads();
    if (grp == 0) {
        float S = reds[0][col] + reds[1][col] + reds[2][col] + reds[3][col];
        float Q = redq[0][col] + redq[1][col] + redq[2][col] + redq[3][col];
        float m = S * (1.0f / 64.0f);
        float v = Q * (1.0f / 64.0f) - m * m;
        float sc = g3[col] * rsqrtf(v + EPSV);
        lsc[col] = sc;
        lsh[col] = b3[col] - m * sc;
    }
    __syncthreads();
    float sc = lsc[col], sh = lsh[col];
    #pragma unroll
    for (int g = 0; g < 16; ++g)
        z[(grp * 16 + g) * 256 + col] = fmaf(acc[g], sc, sh);
}

// ---------------- head part 2: out = z @ W_fc2 + b_fc2, (64 x 10) ----------------
__global__ __launch_bounds__(640) void fc2_kernel(
    const float* __restrict__ z, const float* __restrict__ W_fc2,
    const float* __restrict__ b_fc2, float* __restrict__ out)
{
    int t = threadIdx.x;
    int g = t / 10, o = t % 10;
    float acc = b_fc2[o];
    for (int c = 0; c < 256; ++c)
        acc = fmaf(z[g * 256 + c], W_fc2[c * 10 + o], acc);
    out[g * 10 + o] = acc;
}

extern "C" void kernel_launch(void* const* d_in, const int* in_sizes, int n_in,
                              void* d_out, int out_size, void* d_ws, size_t ws_size,
                              hipStream_t stream) {
    const int N = 100000, E = 1600000;

    const float* x          = (const float*)d_in[0];
    const int*   membership = (const int*)d_in[1];
    const int*   edges      = (const int*)d_in[2];
    const float* W_rel1     = (const float*)d_in[3];
    const float* b_rel1     = (const float*)d_in[4];
    const float* W_root1    = (const float*)d_in[5];
    const float* W_rel2     = (const float*)d_in[6];
    const float* b_rel2     = (const float*)d_in[7];
    const float* W_root2    = (const float*)d_in[8];
    const float* g1         = (const float*)d_in[9];
    const float* b1         = (const float*)d_in[10];
    const float* g2         = (const float*)d_in[11];
    const float* b2         = (const float*)d_in[12];
    const float* W_fc1      = (const float*)d_in[13];
    const float* b_fc1      = (const float*)d_in[14];
    const float* g3         = (const float*)d_in[15];
    const float* b3         = (const float*)d_in[16];
    const float* W_fc2      = (const float*)d_in[17];
    const float* b_fc2      = (const float*)d_in[18];

    // workspace layout (4B elements)
    int*   wsi      = (int*)d_ws;
    float* wsf      = (float*)d_ws;
    int*   gbcnt    = wsi + 0;        // 784
    float* stats    = wsf + 784;      // 512
    float* pooled   = wsf + 1296;     // 4096
    int*   bbase    = wsi + 5392;     // 800 (NB+1)
    int*   gcursor  = wsi + 6192;     // 784
    int*   gstart   = wsi + 6976;     // 128
    int*   rowstart = wsi + 7104;     // 100064
    int*   pk       = wsi + 107168;   // 1600000
    int*   srcs     = wsi + 1707168;  // 1600000
    float* agg1     = wsf + 3307168;  // 300032
    float* u1       = wsf + 3607200;  // 6400000 (becomes t in-place)
    float* pbuf     = wsf + 10007200; // 6400000
    float* z        = wsf + 16407200; // 16384   (total 16,423,584 elems = 62.6 MiB)

    float* sums1  = stats + 0;
    float* sumsq1 = stats + 64;
    float* sums2  = stats + 128;
    float* sumsq2 = stats + 192;
    float* scale1 = stats + 256;
    float* shift1 = stats + 320;
    float* scale2 = stats + 384;
    float* shift2 = stats + 448;

    // zero gbcnt | stats | pooled (contiguous prefix, 21.6 KB)
    hipMemsetAsync(d_ws, 0, (size_t)(784 + 512 + 4096) * 4, stream);

    // CSR build: bucket-group then per-bucket fine sort (writes stay in 8KB windows)
    const int EB = (E + 4095) / 4096;  // 391
    bhist_kernel<<<EB, 256, 0, stream>>>(edges, gbcnt, E);
    bscan_kernel<<<1, 256, 0, stream>>>(gbcnt, bbase, gcursor, E);
    bfill_kernel<<<EB, 256, 0, stream>>>(edges, gcursor, pk, E);
    bsort_kernel<<<NB, 256, 0, stream>>>(pk, bbase, rowstart, srcs, N, E);
    bounds_kernel<<<(N + 256) / 256, 256, 0, stream>>>(membership, gstart, N);

    // layer 1
    gather1_kernel<<<(N + 255) / 256, 256, 0, stream>>>(x, rowstart, srcs, agg1, N);
    layer1_kernel<<<(N + 127) / 128, 256, 0, stream>>>(
        x, agg1, W_rel1, b_rel1, W_root1, u1, sums1, sumsq1, N);
    bnscale_kernel<<<1, 64, 0, stream>>>(sums1, sumsq1, g1, b1, 1.0f / N, 64, scale1, shift1);

    // layer 2: dense transform (t in-place over u1, p separate) then streaming gather
    transform_kernel<<<(N + 63) / 64, 256, 0, stream>>>(
        u1, pbuf, scale1, shift1, W_rel2, b_rel2, W_root2, N);
    {
        const int GRID2 = 2048;
        int chunk = (N + GRID2 * 4 - 1) / (GRID2 * 4);  // 13
        gatherpool_kernel<<<GRID2, 256, 0, stream>>>(
            u1, pbuf, rowstart, srcs, membership, pooled, sums2, sumsq2, N, chunk);
    }
    bnscale_kernel<<<1, 64, 0, stream>>>(sums2, sumsq2, g2, b2, 1.0f / N, 64, scale2, shift2);

    // head
    fc1_kernel<<<1, 1024, 0, stream>>>(pooled, gstart, scale2, shift2,
                                       W_fc1, b_fc1, g3, b3, z);
    fc2_kernel<<<1, 640, 0, stream>>>(z, W_fc2, b_fc2, (float*)d_out);
}

// Round 6
// 310.952 us; speedup vs baseline: 3.3955x; 1.0417x over previous
//
#include <hip/hip_runtime.h>
#include <hip/hip_bf16.h>

#define EPSV 1e-5f
#define BKT 128            // nodes per bucket
#define NB  782            // ceil(100000/128)

typedef __hip_bfloat16 bf16;

__device__ inline void atomAddG(float* p, float v) { unsafeAtomicAdd(p, v); }

// ---------------- bucket histogram (LDS-aggregated) ----------------
__global__ __launch_bounds__(256) void bhist_kernel(
    const int* __restrict__ edges, int* __restrict__ gbcnt, int E)
{
    __shared__ int lh[NB];
    const int t = threadIdx.x;
    for (int i = t; i < NB; i += 256) lh[i] = 0;
    __syncthreads();
    const int base = blockIdx.x * 4096;
    #pragma unroll
    for (int i = 0; i < 16; ++i) {
        int e = base + i * 256 + t;
        if (e < E) atomicAdd(&lh[edges[E + e] >> 7], 1);
    }
    __syncthreads();
    for (int i = t; i < NB; i += 256) {
        int c = lh[i];
        if (c) atomicAdd(&gbcnt[i], c);
    }
}

// ------- bucket scan (single block): bbase exclusive + cursor copy -------
__global__ __launch_bounds__(256) void bscan_kernel(
    const int* __restrict__ gbcnt, int* __restrict__ bbase,
    int* __restrict__ gcursor, int E)
{
    __shared__ int l[256];
    const int t = threadIdx.x;
    int b0 = t * 4;
    int v0 = (b0 + 0 < NB) ? gbcnt[b0 + 0] : 0;
    int v1 = (b0 + 1 < NB) ? gbcnt[b0 + 1] : 0;
    int v2 = (b0 + 2 < NB) ? gbcnt[b0 + 2] : 0;
    int v3 = (b0 + 3 < NB) ? gbcnt[b0 + 3] : 0;
    int tot = v0 + v1 + v2 + v3;
    l[t] = tot;
    __syncthreads();
    for (int o = 1; o < 256; o <<= 1) {
        int add = (t >= o) ? l[t - o] : 0;
        __syncthreads();
        l[t] += add;
        __syncthreads();
    }
    int off = l[t] - tot;
    if (b0 + 0 < NB) { bbase[b0 + 0] = off;                gcursor[b0 + 0] = off; }
    if (b0 + 1 < NB) { bbase[b0 + 1] = off + v0;           gcursor[b0 + 1] = off + v0; }
    if (b0 + 2 < NB) { bbase[b0 + 2] = off + v0 + v1;      gcursor[b0 + 2] = off + v0 + v1; }
    if (b0 + 3 < NB) { bbase[b0 + 3] = off + v0 + v1 + v2; gcursor[b0 + 3] = off + v0 + v1 + v2; }
    if (t == 0) bbase[NB] = E;
}

// ------- bucket fill: pk = (src<<7)|(dst&127), grouped by bucket -------
__global__ __launch_bounds__(256) void bfill_kernel(
    const int* __restrict__ edges, int* __restrict__ gcursor,
    int* __restrict__ pk, int E)
{
    __shared__ int lh[NB];
    __shared__ int lbase[NB];
    const int t = threadIdx.x;
    for (int i = t; i < NB; i += 256) lh[i] = 0;
    __syncthreads();
    const int base = blockIdx.x * 4096;
    int dv[16];
    #pragma unroll
    for (int i = 0; i < 16; ++i) {
        int e = base + i * 256 + t;
        dv[i] = (e < E) ? edges[E + e] : -1;
        if (dv[i] >= 0) atomicAdd(&lh[dv[i] >> 7], 1);
    }
    __syncthreads();
    for (int i = t; i < NB; i += 256) {
        int c = lh[i];
        lbase[i] = c ? atomicAdd(&gcursor[i], c) : 0;
        lh[i] = 0;
    }
    __syncthreads();
    #pragma unroll
    for (int i = 0; i < 16; ++i) {
        int e = base + i * 256 + t;
        if (dv[i] >= 0) {
            int s = edges[e];
            int b = dv[i] >> 7;
            int pos = lbase[b] + atomicAdd(&lh[b], 1);
            pk[pos] = (s << 7) | (dv[i] & 127);
        }
    }
}

// ---- per-bucket fine sort + fused x-gather: CSR rowstart + srcs + agg1 ----
__global__ __launch_bounds__(256) void bsort_kernel(
    const int* __restrict__ pk, const int* __restrict__ bbase,
    const float* __restrict__ x,
    int* __restrict__ rowstart, int* __restrict__ srcs,
    float* __restrict__ agg1, int N, int E)
{
    __shared__ int lcnt[BKT];
    __shared__ int lscan[BKT];
    __shared__ float accx[BKT * 4];
    const int t = threadIdx.x;
    const int b = blockIdx.x;
    const int e0 = bbase[b], e1 = bbase[b + 1];
    if (t < BKT) lcnt[t] = 0;
    for (int i = t; i < BKT * 4; i += 256) accx[i] = 0.f;
    __syncthreads();
    for (int e = e0 + t; e < e1; e += 256) atomicAdd(&lcnt[pk[e] & 127], 1);
    __syncthreads();
    if (t < BKT) lscan[t] = lcnt[t];
    __syncthreads();
    for (int o = 1; o < BKT; o <<= 1) {
        int add = (t < BKT && t >= o) ? lscan[t - o] : 0;
        __syncthreads();
        if (t < BKT) lscan[t] += add;
        __syncthreads();
    }
    const int n0 = b * BKT;
    if (t < BKT) {
        int excl = lscan[t] - lcnt[t];
        lscan[t] = excl;                 // per-local-dst base offset
        int n = n0 + t;
        if (n <= N) rowstart[n] = e0 + excl;   // last bucket's t=32 writes rowstart[N]=E
        lcnt[t] = 0;                     // reuse as cursor
    }
    __syncthreads();
    for (int e = e0 + t; e < e1; e += 256) {
        int v = pk[e];
        int ld = v & 127;
        int s = v >> 7;
        int pos = atomicAdd(&lcnt[ld], 1);
        srcs[e0 + lscan[ld] + pos] = s;
        atomicAdd(&accx[ld * 4 + 0], x[s * 3 + 0]);
        atomicAdd(&accx[ld * 4 + 1], x[s * 3 + 1]);
        atomicAdd(&accx[ld * 4 + 2], x[s * 3 + 2]);
    }
    __syncthreads();
    for (int i = t; i < BKT * 3; i += 256) {
        int nl = i / 3, c = i - nl * 3;
        int n = n0 + nl;
        if (n < N) agg1[n * 3 + c] = accx[nl * 4 + c];
    }
}

// ------- graph boundaries from sorted membership: gstart[g] for g=0..64 -------
__global__ __launch_bounds__(256) void bounds_kernel(
    const int* __restrict__ membership, int* __restrict__ gstart, int N)
{
    int n = blockIdx.x * 256 + threadIdx.x;
    if (n > N) return;
    int mp = (n == 0) ? -1 : membership[n - 1];
    int mc = (n == N) ? 64 : membership[n];
    for (int g = mp + 1; g <= mc; ++g) gstart[g] = n;
}

// ------- layer 1 dense: u1 = relu(agg1@W_rel1 + b_rel1 + x@W_root1); stats -------
__global__ __launch_bounds__(256) void layer1_kernel(
    const float* __restrict__ x, const float* __restrict__ agg1,
    const float* __restrict__ W_rel1, const float* __restrict__ b_rel1,
    const float* __restrict__ W_root1,
    float* __restrict__ u1, float* __restrict__ sums, float* __restrict__ sumsq,
    int N)
{
    const int t = threadIdx.x;
    const int f = t & 63, r4 = t >> 6;
    const float wr0 = W_rel1[f], wr1 = W_rel1[64 + f], wr2 = W_rel1[128 + f];
    const float wo0 = W_root1[f], wo1 = W_root1[64 + f], wo2 = W_root1[128 + f];
    const float bb = b_rel1[f];
    float ps = 0.f, pq = 0.f;
    const int base = blockIdx.x * 128;
    for (int i = r4; i < 128; i += 4) {
        int n = base + i;
        if (n >= N) break;
        float a0 = agg1[n * 3 + 0], a1 = agg1[n * 3 + 1], a2 = agg1[n * 3 + 2];
        float x0 = x[n * 3 + 0], x1 = x[n * 3 + 1], x2 = x[n * 3 + 2];
        float v = bb;
        v = fmaf(a0, wr0, v); v = fmaf(a1, wr1, v); v = fmaf(a2, wr2, v);
        v = fmaf(x0, wo0, v); v = fmaf(x1, wo1, v); v = fmaf(x2, wo2, v);
        v = fmaxf(v, 0.f);
        u1[n * 64 + f] = v;
        ps += v; pq += v * v;
    }
    __shared__ float lsum[4][64], lsq[4][64];
    lsum[r4][f] = ps; lsq[r4][f] = pq;
    __syncthreads();
    if (r4 == 0) {
        float s = lsum[0][f] + lsum[1][f] + lsum[2][f] + lsum[3][f];
        float q = lsq[0][f] + lsq[1][f] + lsq[2][f] + lsq[3][f];
        atomAddG(&sums[f], s);
        atomAddG(&sumsq[f], q);
    }
}

// ------------- BN: scale = g*rsqrt(var+eps), shift = b - mean*scale -------------
__global__ void bnscale_kernel(const float* __restrict__ sums, const float* __restrict__ sumsq,
                               const float* __restrict__ g, const float* __restrict__ b,
                               float invn, int C,
                               float* __restrict__ scale, float* __restrict__ shift)
{
    int f = blockIdx.x * blockDim.x + threadIdx.x;
    if (f >= C) return;
    float m = sums[f] * invn;
    float v = sumsq[f] * invn - m * m;
    float sc = g[f] * rsqrtf(v + EPSV);
    scale[f] = sc;
    shift[f] = b[f] - m * sc;
}

// ---- transform: h1 = BN1(u1); t[n] = h1@W_rel2 -> bf16; p[n] = h1@W_root2+b -> bf16 ----
__global__ __launch_bounds__(256) void transform_kernel(
    const float* __restrict__ u1,
    bf16* __restrict__ tb, bf16* __restrict__ pb,
    const float* __restrict__ scale1, const float* __restrict__ shift1,
    const float* __restrict__ W_rel2, const float* __restrict__ b_rel2,
    const float* __restrict__ W_root2, int N)
{
    __shared__ float lWrel[4096];
    __shared__ float lWroot[4096];
    __shared__ float rowH[4][64];
    const int t = threadIdx.x;
    const int f = t & 63, r4 = t >> 6;
    for (int i = t; i < 4096; i += 256) {
        lWrel[i] = W_rel2[i];
        lWroot[i] = W_root2[i];
    }
    __syncthreads();
    const float sc1 = scale1[f], sh1 = shift1[f], bb = b_rel2[f];
    const int base = blockIdx.x * 64;
    for (int i = 0; i < 16; ++i) {
        int n = base + i * 4 + r4;
        bool ok = (n < N);
        if (ok) rowH[r4][f] = fmaf(u1[n * 64 + f], sc1, sh1);
        __syncthreads();
        if (ok) {
            float o1 = 0.f, o2 = bb;
            #pragma unroll
            for (int k = 0; k < 64; ++k) {
                float h = rowH[r4][k];
                o1 = fmaf(h, lWrel[k * 64 + f], o1);
                o2 = fmaf(h, lWroot[k * 64 + f], o2);
            }
            tb[n * 64 + f] = __float2bfloat16(o1);
            pb[n * 64 + f] = __float2bfloat16(o2);
        }
        __syncthreads();
    }
}

// ---- gather+pool: u2[n] = relu(sum_src t[src] + p[n]); BN2 stats; pooled sums.
// ---- Wave per node-chunk, lane = feature, 16-deep bf16 load pipeline. ----
__global__ __launch_bounds__(256, 8) void gatherpool_kernel(
    const bf16* __restrict__ tb, const bf16* __restrict__ pb,
    const int* __restrict__ rowstart, const int* __restrict__ srcs,
    const int* __restrict__ membership,
    float* __restrict__ pooled, float* __restrict__ sums, float* __restrict__ sumsq,
    int N, int chunk)
{
    __shared__ float red[4][64];
    const int tid = threadIdx.x;
    const int w = tid >> 6, f = tid & 63;
    const int gw = __builtin_amdgcn_readfirstlane(blockIdx.x * 4 + w);
    const int n0 = gw * chunk;
    const int n1 = min(N, n0 + chunk);
    float ps = 0.f, pq = 0.f, pacc = 0.f;
    int curg = (n0 < N) ? membership[n0] : -1;

    for (int n = n0; n < n1; ++n) {
        int s0 = rowstart[n], s1 = rowstart[n + 1];
        float acc = __bfloat162float(pb[n * 64 + f]);
        int j = s0;
        for (; j + 15 < s1; j += 16) {
            float vs[16];
            #pragma unroll
            for (int q = 0; q < 16; ++q)
                vs[q] = __bfloat162float(tb[srcs[j + q] * 64 + f]);
            float sA = ((vs[0] + vs[1]) + (vs[2] + vs[3])) + ((vs[4] + vs[5]) + (vs[6] + vs[7]));
            float sB = ((vs[8] + vs[9]) + (vs[10] + vs[11])) + ((vs[12] + vs[13]) + (vs[14] + vs[15]));
            acc += sA + sB;
        }
        for (; j + 3 < s1; j += 4) {
            float v0 = __bfloat162float(tb[srcs[j + 0] * 64 + f]);
            float v1 = __bfloat162float(tb[srcs[j + 1] * 64 + f]);
            float v2 = __bfloat162float(tb[srcs[j + 2] * 64 + f]);
            float v3 = __bfloat162float(tb[srcs[j + 3] * 64 + f]);
            acc += (v0 + v1) + (v2 + v3);
        }
        for (; j < s1; ++j) acc += __bfloat162float(tb[srcs[j] * 64 + f]);

        acc = fmaxf(acc, 0.f);
        ps += acc; pq += acc * acc;

        int g = membership[n];
        if (g != curg) {
            atomAddG(&pooled[curg * 64 + f], pacc);
            pacc = 0.f;
            curg = g;
        }
        pacc += acc;
    }
    if (curg >= 0) atomAddG(&pooled[curg * 64 + f], pacc);

    red[w][f] = ps;
    __syncthreads();
    if (w == 0) atomAddG(&sums[f], red[0][f] + red[1][f] + red[2][f] + red[3][f]);
    __syncthreads();
    red[w][f] = pq;
    __syncthreads();
    if (w == 0) atomAddG(&sumsq[f], red[0][f] + red[1][f] + red[2][f] + red[3][f]);
}

// ---- head part 1: pm = BN2(pooled/cnt); z = BN3(relu(pm@W_fc1+b_fc1)) ----
__global__ __launch_bounds__(1024) void fc1_kernel(
    const float* __restrict__ pooled, const int* __restrict__ gstart,
    const float* __restrict__ scale2, const float* __restrict__ shift2,
    const float* __restrict__ W_fc1, const float* __restrict__ b_fc1,
    const float* __restrict__ g3, const float* __restrict__ b3,
    float* __restrict__ z)
{
    __shared__ float pm[4096];
    __shared__ float reds[4][256], redq[4][256];
    __shared__ float lsc[256], lsh[256];
    const int t = threadIdx.x;
    for (int i = t; i < 4096; i += 1024) {
        int g = i >> 6, f = i & 63;
        float c = fmaxf((float)(gstart[g + 1] - gstart[g]), 1.0f);
        pm[i] = fmaf(pooled[i] / c, scale2[f], shift2[f]);
    }
    __syncthreads();
    const int col = t & 255, grp = t >> 8;
    float acc[16];
    const float bc = b_fc1[col];
    #pragma unroll
    for (int g = 0; g < 16; ++g) acc[g] = bc;
    for (int k = 0; k < 64; ++k) {
        float wv = W_fc1[k * 256 + col];
        #pragma unroll
        for (int g = 0; g < 16; ++g)
            acc[g] = fmaf(pm[(grp * 16 + g) * 64 + k], wv, acc[g]);
    }
    float s = 0.f, q = 0.f;
    #pragma unroll
    for (int g = 0; g < 16; ++g) {
        acc[g] = fmaxf(acc[g], 0.f);
        s += acc[g]; q += acc[g] * acc[g];
    }
    reds[grp][col] = s; redq[grp][col] = q;
    __syncthreads();
    if (grp == 0) {
        float S = reds[0][col] + reds[1][col] + reds[2][col] + reds[3][col];
        float Q = redq[0][col] + redq[1][col] + redq[2][col] + redq[3][col];
        float m = S * (1.0f / 64.0f);
        float v = Q * (1.0f / 64.0f) - m * m;
        float sc = g3[col] * rsqrtf(v + EPSV);
        lsc[col] = sc;
        lsh[col] = b3[col] - m * sc;
    }
    __syncthreads();
    float sc = lsc[col], sh = lsh[col];
    #pragma unroll
    for (int g = 0; g < 16; ++g)
        z[(grp * 16 + g) * 256 + col] = fmaf(acc[g], sc, sh);
}

// ---------------- head part 2: out = z @ W_fc2 + b_fc2, (64 x 10) ----------------
__global__ __launch_bounds__(640) void fc2_kernel(
    const float* __restrict__ z, const float* __restrict__ W_fc2,
    const float* __restrict__ b_fc2, float* __restrict__ out)
{
    int t = threadIdx.x;
    int g = t / 10, o = t % 10;
    float acc = b_fc2[o];
    for (int c = 0; c < 256; ++c)
        acc = fmaf(z[g * 256 + c], W_fc2[c * 10 + o], acc);
    out[g * 10 + o] = acc;
}

extern "C" void kernel_launch(void* const* d_in, const int* in_sizes, int n_in,
                              void* d_out, int out_size, void* d_ws, size_t ws_size,
                              hipStream_t stream) {
    const int N = 100000, E = 1600000;

    const float* x          = (const float*)d_in[0];
    const int*   membership = (const int*)d_in[1];
    const int*   edges      = (const int*)d_in[2];
    const float* W_rel1     = (const float*)d_in[3];
    const float* b_rel1     = (const float*)d_in[4];
    const float* W_root1    = (const float*)d_in[5];
    const float* W_rel2     = (const float*)d_in[6];
    const float* b_rel2     = (const float*)d_in[7];
    const float* W_root2    = (const float*)d_in[8];
    const float* g1         = (const float*)d_in[9];
    const float* b1         = (const float*)d_in[10];
    const float* g2         = (const float*)d_in[11];
    const float* b2         = (const float*)d_in[12];
    const float* W_fc1      = (const float*)d_in[13];
    const float* b_fc1      = (const float*)d_in[14];
    const float* g3         = (const float*)d_in[15];
    const float* b3         = (const float*)d_in[16];
    const float* W_fc2      = (const float*)d_in[17];
    const float* b_fc2      = (const float*)d_in[18];

    // workspace layout (4B elements)
    int*   wsi      = (int*)d_ws;
    float* wsf      = (float*)d_ws;
    int*   gbcnt    = wsi + 0;        // 784
    float* stats    = wsf + 784;      // 512
    float* pooled   = wsf + 1296;     // 4096
    int*   bbase    = wsi + 5392;     // 800 (NB+1)
    int*   gcursor  = wsi + 6192;     // 784
    int*   gstart   = wsi + 6976;     // 128
    int*   rowstart = wsi + 7104;     // 100064
    int*   pk       = wsi + 107168;   // 1600000
    int*   srcs     = wsi + 1707168;  // 1600000
    float* agg1     = wsf + 3307168;  // 300032
    float* u1       = wsf + 3607200;  // 6400000
    bf16*  tb       = (bf16*)(wsf + 10007200); // 6400000 bf16 = 3200000 floats
    bf16*  pb       = (bf16*)(wsf + 13207200); // 6400000 bf16 = 3200000 floats
    float* z        = wsf + 16407200; // 16384  (total 16,423,584 elems = 62.6 MiB)

    float* sums1  = stats + 0;
    float* sumsq1 = stats + 64;
    float* sums2  = stats + 128;
    float* sumsq2 = stats + 192;
    float* scale1 = stats + 256;
    float* shift1 = stats + 320;
    float* scale2 = stats + 384;
    float* shift2 = stats + 448;

    // zero gbcnt | stats | pooled (contiguous prefix, 21.6 KB)
    hipMemsetAsync(d_ws, 0, (size_t)(784 + 512 + 4096) * 4, stream);

    // CSR build: bucket-group, then per-bucket fine sort fused with x-gather
    const int EB = (E + 4095) / 4096;  // 391
    bhist_kernel<<<EB, 256, 0, stream>>>(edges, gbcnt, E);
    bscan_kernel<<<1, 256, 0, stream>>>(gbcnt, bbase, gcursor, E);
    bfill_kernel<<<EB, 256, 0, stream>>>(edges, gcursor, pk, E);
    bsort_kernel<<<NB, 256, 0, stream>>>(pk, bbase, x, rowstart, srcs, agg1, N, E);
    bounds_kernel<<<(N + 256) / 256, 256, 0, stream>>>(membership, gstart, N);

    // layer 1 dense + BN1
    layer1_kernel<<<(N + 127) / 128, 256, 0, stream>>>(
        x, agg1, W_rel1, b_rel1, W_root1, u1, sums1, sumsq1, N);
    bnscale_kernel<<<1, 64, 0, stream>>>(sums1, sumsq1, g1, b1, 1.0f / N, 64, scale1, shift1);

    // layer 2: dense transform (bf16 t/p) then streaming bf16 gather + pool
    transform_kernel<<<(N + 63) / 64, 256, 0, stream>>>(
        u1, tb, pb, scale1, shift1, W_rel2, b_rel2, W_root2, N);
    {
        const int GRID2 = 2048;
        int chunk = (N + GRID2 * 4 - 1) / (GRID2 * 4);  // 13
        gatherpool_kernel<<<GRID2, 256, 0, stream>>>(
            tb, pb, rowstart, srcs, membership, pooled, sums2, sumsq2, N, chunk);
    }
    bnscale_kernel<<<1, 64, 0, stream>>>(sums2, sumsq2, g2, b2, 1.0f / N, 64, scale2, shift2);

    // head
    fc1_kernel<<<1, 1024, 0, stream>>>(pooled, gstart, scale2, shift2,
                                       W_fc1, b_fc1, g3, b3, z);
    fc2_kernel<<<1, 640, 0, stream>>>(z, W_fc2, b_fc2, (float*)d_out);
}

// Round 7
// 254.340 us; speedup vs baseline: 4.1513x; 1.2226x over previous
//
#include <hip/hip_runtime.h>
#include <hip/hip_bf16.h>

#define EPSV 1e-5f
#define BKT 128            // nodes per bucket
#define NB  782            // ceil(100000/128)

typedef __hip_bfloat16 bf16;
typedef __attribute__((ext_vector_type(8))) short short8v;
typedef __attribute__((ext_vector_type(4))) float f32x4v;

__device__ inline void atomAddG(float* p, float v) { unsafeAtomicAdd(p, v); }
__device__ inline unsigned short f2bf(float v) {
    bf16 h = __float2bfloat16(v);
    return *reinterpret_cast<unsigned short*>(&h);
}

// ---------------- bucket histogram (LDS-aggregated) ----------------
__global__ __launch_bounds__(256) void bhist_kernel(
    const int* __restrict__ edges, int* __restrict__ gbcnt, int E)
{
    __shared__ int lh[NB];
    const int t = threadIdx.x;
    for (int i = t; i < NB; i += 256) lh[i] = 0;
    __syncthreads();
    const int base = blockIdx.x * 4096;
    #pragma unroll
    for (int i = 0; i < 16; ++i) {
        int e = base + i * 256 + t;
        if (e < E) atomicAdd(&lh[edges[E + e] >> 7], 1);
    }
    __syncthreads();
    for (int i = t; i < NB; i += 256) {
        int c = lh[i];
        if (c) atomicAdd(&gbcnt[i], c);
    }
}

// ------- bucket scan (single block): bbase exclusive + cursor copy -------
__global__ __launch_bounds__(256) void bscan_kernel(
    const int* __restrict__ gbcnt, int* __restrict__ bbase,
    int* __restrict__ gcursor, int E)
{
    __shared__ int l[256];
    const int t = threadIdx.x;
    int b0 = t * 4;
    int v0 = (b0 + 0 < NB) ? gbcnt[b0 + 0] : 0;
    int v1 = (b0 + 1 < NB) ? gbcnt[b0 + 1] : 0;
    int v2 = (b0 + 2 < NB) ? gbcnt[b0 + 2] : 0;
    int v3 = (b0 + 3 < NB) ? gbcnt[b0 + 3] : 0;
    int tot = v0 + v1 + v2 + v3;
    l[t] = tot;
    __syncthreads();
    for (int o = 1; o < 256; o <<= 1) {
        int add = (t >= o) ? l[t - o] : 0;
        __syncthreads();
        l[t] += add;
        __syncthreads();
    }
    int off = l[t] - tot;
    if (b0 + 0 < NB) { bbase[b0 + 0] = off;                gcursor[b0 + 0] = off; }
    if (b0 + 1 < NB) { bbase[b0 + 1] = off + v0;           gcursor[b0 + 1] = off + v0; }
    if (b0 + 2 < NB) { bbase[b0 + 2] = off + v0 + v1;      gcursor[b0 + 2] = off + v0 + v1; }
    if (b0 + 3 < NB) { bbase[b0 + 3] = off + v0 + v1 + v2; gcursor[b0 + 3] = off + v0 + v1 + v2; }
    if (t == 0) bbase[NB] = E;
}

// ------- bucket fill: pk = (src<<7)|(dst&127), grouped by bucket -------
__global__ __launch_bounds__(256) void bfill_kernel(
    const int* __restrict__ edges, int* __restrict__ gcursor,
    int* __restrict__ pk, int E)
{
    __shared__ int lh[NB];
    __shared__ int lbase[NB];
    const int t = threadIdx.x;
    for (int i = t; i < NB; i += 256) lh[i] = 0;
    __syncthreads();
    const int base = blockIdx.x * 4096;
    int dv[16];
    #pragma unroll
    for (int i = 0; i < 16; ++i) {
        int e = base + i * 256 + t;
        dv[i] = (e < E) ? edges[E + e] : -1;
        if (dv[i] >= 0) atomicAdd(&lh[dv[i] >> 7], 1);
    }
    __syncthreads();
    for (int i = t; i < NB; i += 256) {
        int c = lh[i];
        lbase[i] = c ? atomicAdd(&gcursor[i], c) : 0;
        lh[i] = 0;
    }
    __syncthreads();
    #pragma unroll
    for (int i = 0; i < 16; ++i) {
        int e = base + i * 256 + t;
        if (dv[i] >= 0) {
            int s = edges[e];
            int b = dv[i] >> 7;
            int pos = lbase[b] + atomicAdd(&lh[b], 1);
            pk[pos] = (s << 7) | (dv[i] & 127);
        }
    }
}

// ---- per-bucket fine sort + fused x-gather: CSR rowstart + srcs + agg1 ----
__global__ __launch_bounds__(256) void bsort_kernel(
    const int* __restrict__ pk, const int* __restrict__ bbase,
    const float* __restrict__ x,
    int* __restrict__ rowstart, int* __restrict__ srcs,
    float* __restrict__ agg1, int N, int E)
{
    __shared__ int lcnt[BKT];
    __shared__ int lscan[BKT];
    __shared__ float accx[BKT * 4];
    const int t = threadIdx.x;
    const int b = blockIdx.x;
    const int e0 = bbase[b], e1 = bbase[b + 1];
    if (t < BKT) lcnt[t] = 0;
    for (int i = t; i < BKT * 4; i += 256) accx[i] = 0.f;
    __syncthreads();
    for (int e = e0 + t; e < e1; e += 256) atomicAdd(&lcnt[pk[e] & 127], 1);
    __syncthreads();
    if (t < BKT) lscan[t] = lcnt[t];
    __syncthreads();
    for (int o = 1; o < BKT; o <<= 1) {
        int add = (t < BKT && t >= o) ? lscan[t - o] : 0;
        __syncthreads();
        if (t < BKT) lscan[t] += add;
        __syncthreads();
    }
    const int n0 = b * BKT;
    if (t < BKT) {
        int excl = lscan[t] - lcnt[t];
        lscan[t] = excl;                 // per-local-dst base offset
        int n = n0 + t;
        if (n <= N) rowstart[n] = e0 + excl;   // last bucket's t=32 writes rowstart[N]=E
        lcnt[t] = 0;                     // reuse as cursor
    }
    __syncthreads();
    for (int e = e0 + t; e < e1; e += 256) {
        int v = pk[e];
        int ld = v & 127;
        int s = v >> 7;
        int pos = atomicAdd(&lcnt[ld], 1);
        srcs[e0 + lscan[ld] + pos] = s;
        atomicAdd(&accx[ld * 4 + 0], x[s * 3 + 0]);
        atomicAdd(&accx[ld * 4 + 1], x[s * 3 + 1]);
        atomicAdd(&accx[ld * 4 + 2], x[s * 3 + 2]);
    }
    __syncthreads();
    for (int i = t; i < BKT * 3; i += 256) {
        int nl = i / 3, c = i - nl * 3;
        int n = n0 + nl;
        if (n < N) agg1[n * 3 + c] = accx[nl * 4 + c];
    }
}

// ------- graph boundaries from sorted membership: gstart[g] for g=0..64 -------
__global__ __launch_bounds__(256) void bounds_kernel(
    const int* __restrict__ membership, int* __restrict__ gstart, int N)
{
    int n = blockIdx.x * 256 + threadIdx.x;
    if (n > N) return;
    int mp = (n == 0) ? -1 : membership[n - 1];
    int mc = (n == N) ? 64 : membership[n];
    for (int g = mp + 1; g <= mc; ++g) gstart[g] = n;
}

// ------- layer 1 dense: u1b = bf16(relu(agg1@W_rel1 + b_rel1 + x@W_root1)); stats -------
__global__ __launch_bounds__(256) void layer1_kernel(
    const float* __restrict__ x, const float* __restrict__ agg1,
    const float* __restrict__ W_rel1, const float* __restrict__ b_rel1,
    const float* __restrict__ W_root1,
    unsigned short* __restrict__ u1b, float* __restrict__ sums, float* __restrict__ sumsq,
    int N)
{
    const int t = threadIdx.x;
    const int f = t & 63, r4 = t >> 6;
    const float wr0 = W_rel1[f], wr1 = W_rel1[64 + f], wr2 = W_rel1[128 + f];
    const float wo0 = W_root1[f], wo1 = W_root1[64 + f], wo2 = W_root1[128 + f];
    const float bb = b_rel1[f];
    float ps = 0.f, pq = 0.f;
    const int base = blockIdx.x * 128;
    for (int i = r4; i < 128; i += 4) {
        int n = base + i;
        if (n >= N) break;
        float a0 = agg1[n * 3 + 0], a1 = agg1[n * 3 + 1], a2 = agg1[n * 3 + 2];
        float x0 = x[n * 3 + 0], x1 = x[n * 3 + 1], x2 = x[n * 3 + 2];
        float v = bb;
        v = fmaf(a0, wr0, v); v = fmaf(a1, wr1, v); v = fmaf(a2, wr2, v);
        v = fmaf(x0, wo0, v); v = fmaf(x1, wo1, v); v = fmaf(x2, wo2, v);
        v = fmaxf(v, 0.f);
        u1b[n * 64 + f] = f2bf(v);
        ps += v; pq += v * v;
    }
    __shared__ float lsum[4][64], lsq[4][64];
    lsum[r4][f] = ps; lsq[r4][f] = pq;
    __syncthreads();
    if (r4 == 0) {
        float s = lsum[0][f] + lsum[1][f] + lsum[2][f] + lsum[3][f];
        float q = lsq[0][f] + lsq[1][f] + lsq[2][f] + lsq[3][f];
        atomAddG(&sums[f], s);
        atomAddG(&sumsq[f], q);
    }
}

// ------------- BN: scale = g*rsqrt(var+eps), shift = b - mean*scale -------------
__global__ void bnscale_kernel(const float* __restrict__ sums, const float* __restrict__ sumsq,
                               const float* __restrict__ g, const float* __restrict__ b,
                               float invn, int C,
                               float* __restrict__ scale, float* __restrict__ shift)
{
    int f = blockIdx.x * blockDim.x + threadIdx.x;
    if (f >= C) return;
    float m = sums[f] * invn;
    float v = sumsq[f] * invn - m * m;
    float sc = g[f] * rsqrtf(v + EPSV);
    scale[f] = sc;
    shift[f] = b[f] - m * sc;
}

// ---- fold BN1 into layer-2 weights: W' = bf16(diag(sc1)W), c = sh1·W (+b_rel2) ----
__global__ __launch_bounds__(256) void bnfold_kernel(
    const float* __restrict__ scale1, const float* __restrict__ shift1,
    const float* __restrict__ W_rel2, const float* __restrict__ W_root2,
    const float* __restrict__ b_rel2,
    unsigned short* __restrict__ wrelp, unsigned short* __restrict__ wrootp,
    float* __restrict__ crel, float* __restrict__ croot)
{
    __shared__ float r1[4][64], r2[4][64];
    const int t = threadIdx.x, f = t & 63, kg = t >> 6;
    float c1 = 0.f, c2 = 0.f;
    for (int k = kg * 16; k < kg * 16 + 16; ++k) {
        float sc = scale1[k], sh = shift1[k];
        float w1 = W_rel2[k * 64 + f], w2 = W_root2[k * 64 + f];
        wrelp[k * 64 + f] = f2bf(sc * w1);
        wrootp[k * 64 + f] = f2bf(sc * w2);
        c1 = fmaf(sh, w1, c1); c2 = fmaf(sh, w2, c2);
    }
    r1[kg][f] = c1; r2[kg][f] = c2;
    __syncthreads();
    if (kg == 0) {
        crel[f]  = r1[0][f] + r1[1][f] + r1[2][f] + r1[3][f];
        croot[f] = r2[0][f] + r2[1][f] + r2[2][f] + r2[3][f] + b_rel2[f];
    }
}

// ---- MFMA transform: t = u1b@W_rel' + crel; p = u1b@W_root' + croot (bf16 out) ----
// wave handles 16 nodes x 128 outputs = 16 x mfma_f32_16x16x32_bf16
__global__ __launch_bounds__(256) void mfma_transform_kernel(
    const unsigned short* __restrict__ u1b,
    const unsigned short* __restrict__ wrelp, const unsigned short* __restrict__ wrootp,
    const float* __restrict__ crel, const float* __restrict__ croot,
    unsigned short* __restrict__ tb, unsigned short* __restrict__ pb, int NT)
{
    const int wid = (blockIdx.x * blockDim.x + threadIdx.x) >> 6;
    const int lane = threadIdx.x & 63;
    const int q = lane >> 4, r = lane & 15;

    // B fragments: [kc][ftile]; ftile 0..3 -> W_rel' cols 16*ft.., 4..7 -> W_root'
    short8v Bf[2][8];
    float cadd[8];
    #pragma unroll
    for (int kc = 0; kc < 2; ++kc) {
        #pragma unroll
        for (int ft = 0; ft < 8; ++ft) {
            const unsigned short* W = (ft < 4) ? wrelp : wrootp;
            const int f0 = (ft & 3) * 16;
            short8v b;
            #pragma unroll
            for (int j = 0; j < 8; ++j) {
                int k = 32 * kc + 8 * q + j;
                b[j] = (short)W[k * 64 + f0 + r];
            }
            Bf[kc][ft] = b;
        }
    }
    #pragma unroll
    for (int ft = 0; ft < 8; ++ft)
        cadd[ft] = (ft < 4) ? crel[(ft & 3) * 16 + r] : croot[(ft & 3) * 16 + r];

    const int totalWaves = (gridDim.x * blockDim.x) >> 6;
    for (int tile = wid; tile < NT; tile += totalWaves) {
        const int n0 = tile * 16;
        short8v A0 = *(const short8v*)&u1b[(n0 + r) * 64 + 8 * q];        // k 0..31
        short8v A1 = *(const short8v*)&u1b[(n0 + r) * 64 + 32 + 8 * q];   // k 32..63
        #pragma unroll
        for (int ft = 0; ft < 8; ++ft) {
            f32x4v d = {0.f, 0.f, 0.f, 0.f};
            d = __builtin_amdgcn_mfma_f32_16x16x32_bf16(A0, Bf[0][ft], d, 0, 0, 0);
            d = __builtin_amdgcn_mfma_f32_16x16x32_bf16(A1, Bf[1][ft], d, 0, 0, 0);
            unsigned short* O = (ft < 4) ? tb : pb;
            const int f0 = (ft & 3) * 16;
            const float ca = cadd[ft];
            #pragma unroll
            for (int rr = 0; rr < 4; ++rr) {
                int n = n0 + 4 * q + rr;     // D: col = lane&15, row = (lane>>4)*4 + reg
                O[n * 64 + f0 + r] = f2bf(d[rr] + ca);
            }
        }
    }
}

// ---- gather+pool: u2[n] = relu(sum_src t[src] + p[n]); BN2 stats; pooled sums. ----
__global__ __launch_bounds__(256, 8) void gatherpool_kernel(
    const bf16* __restrict__ tb, const bf16* __restrict__ pb,
    const int* __restrict__ rowstart, const int* __restrict__ srcs,
    const int* __restrict__ membership,
    float* __restrict__ pooled, float* __restrict__ sums, float* __restrict__ sumsq,
    int N, int chunk)
{
    __shared__ float red[4][64];
    const int tid = threadIdx.x;
    const int w = tid >> 6, f = tid & 63;
    const int gw = __builtin_amdgcn_readfirstlane(blockIdx.x * 4 + w);
    const int n0 = gw * chunk;
    const int n1 = min(N, n0 + chunk);
    float ps = 0.f, pq = 0.f, pacc = 0.f;
    int curg = (n0 < N) ? membership[n0] : -1;

    for (int n = n0; n < n1; ++n) {
        int s0 = rowstart[n], s1 = rowstart[n + 1];
        float acc = __bfloat162float(pb[n * 64 + f]);
        int j = s0;
        for (; j + 15 < s1; j += 16) {
            float vs[16];
            #pragma unroll
            for (int q = 0; q < 16; ++q)
                vs[q] = __bfloat162float(tb[srcs[j + q] * 64 + f]);
            float sA = ((vs[0] + vs[1]) + (vs[2] + vs[3])) + ((vs[4] + vs[5]) + (vs[6] + vs[7]));
            float sB = ((vs[8] + vs[9]) + (vs[10] + vs[11])) + ((vs[12] + vs[13]) + (vs[14] + vs[15]));
            acc += sA + sB;
        }
        for (; j + 3 < s1; j += 4) {
            float v0 = __bfloat162float(tb[srcs[j + 0] * 64 + f]);
            float v1 = __bfloat162float(tb[srcs[j + 1] * 64 + f]);
            float v2 = __bfloat162float(tb[srcs[j + 2] * 64 + f]);
            float v3 = __bfloat162float(tb[srcs[j + 3] * 64 + f]);
            acc += (v0 + v1) + (v2 + v3);
        }
        for (; j < s1; ++j) acc += __bfloat162float(tb[srcs[j] * 64 + f]);

        acc = fmaxf(acc, 0.f);
        ps += acc; pq += acc * acc;

        int g = membership[n];
        if (g != curg) {
            atomAddG(&pooled[curg * 64 + f], pacc);
            pacc = 0.f;
            curg = g;
        }
        pacc += acc;
    }
    if (curg >= 0) atomAddG(&pooled[curg * 64 + f], pacc);

    red[w][f] = ps;
    __syncthreads();
    if (w == 0) atomAddG(&sums[f], red[0][f] + red[1][f] + red[2][f] + red[3][f]);
    __syncthreads();
    red[w][f] = pq;
    __syncthreads();
    if (w == 0) atomAddG(&sumsq[f], red[0][f] + red[1][f] + red[2][f] + red[3][f]);
}

// ---- head part 1: pm = BN2(pooled/cnt); z = BN3(relu(pm@W_fc1+b_fc1)) ----
__global__ __launch_bounds__(1024) void fc1_kernel(
    const float* __restrict__ pooled, const int* __restrict__ gstart,
    const float* __restrict__ scale2, const float* __restrict__ shift2,
    const float* __restrict__ W_fc1, const float* __restrict__ b_fc1,
    const float* __restrict__ g3, const float* __restrict__ b3,
    float* __restrict__ z)
{
    __shared__ float pm[4096];
    __shared__ float reds[4][256], redq[4][256];
    __shared__ float lsc[256], lsh[256];
    const int t = threadIdx.x;
    for (int i = t; i < 4096; i += 1024) {
        int g = i >> 6, f = i & 63;
        float c = fmaxf((float)(gstart[g + 1] - gstart[g]), 1.0f);
        pm[i] = fmaf(pooled[i] / c, scale2[f], shift2[f]);
    }
    __syncthreads();
    const int col = t & 255, grp = t >> 8;
    float acc[16];
    const float bc = b_fc1[col];
    #pragma unroll
    for (int g = 0; g < 16; ++g) acc[g] = bc;
    for (int k = 0; k < 64; ++k) {
        float wv = W_fc1[k * 256 + col];
        #pragma unroll
        for (int g = 0; g < 16; ++g)
            acc[g] = fmaf(pm[(grp * 16 + g) * 64 + k], wv, acc[g]);
    }
    float s = 0.f, q = 0.f;
    #pragma unroll
    for (int g = 0; g < 16; ++g) {
        acc[g] = fmaxf(acc[g], 0.f);
        s += acc[g]; q += acc[g] * acc[g];
    }
    reds[grp][col] = s; redq[grp][col] = q;
    __syncthreads();
    if (grp == 0) {
        float S = reds[0][col] + reds[1][col] + reds[2][col] + reds[3][col];
        float Q = redq[0][col] + redq[1][col] + redq[2][col] + redq[3][col];
        float m = S * (1.0f / 64.0f);
        float v = Q * (1.0f / 64.0f) - m * m;
        float sc = g3[col] * rsqrtf(v + EPSV);
        lsc[col] = sc;
        lsh[col] = b3[col] - m * sc;
    }
    __syncthreads();
    float sc = lsc[col], sh = lsh[col];
    #pragma unroll
    for (int g = 0; g < 16; ++g)
        z[(grp * 16 + g) * 256 + col] = fmaf(acc[g], sc, sh);
}

// ---------------- head part 2: out = z @ W_fc2 + b_fc2, (64 x 10) ----------------
__global__ __launch_bounds__(640) void fc2_kernel(
    const float* __restrict__ z, const float* __restrict__ W_fc2,
    const float* __restrict__ b_fc2, float* __restrict__ out)
{
    int t = threadIdx.x;
    int g = t / 10, o = t % 10;
    float acc = b_fc2[o];
    for (int c = 0; c < 256; ++c)
        acc = fmaf(z[g * 256 + c], W_fc2[c * 10 + o], acc);
    out[g * 10 + o] = acc;
}

extern "C" void kernel_launch(void* const* d_in, const int* in_sizes, int n_in,
                              void* d_out, int out_size, void* d_ws, size_t ws_size,
                              hipStream_t stream) {
    const int N = 100000, E = 1600000;

    const float* x          = (const float*)d_in[0];
    const int*   membership = (const int*)d_in[1];
    const int*   edges      = (const int*)d_in[2];
    const float* W_rel1     = (const float*)d_in[3];
    const float* b_rel1     = (const float*)d_in[4];
    const float* W_root1    = (const float*)d_in[5];
    const float* W_rel2     = (const float*)d_in[6];
    const float* b_rel2     = (const float*)d_in[7];
    const float* W_root2    = (const float*)d_in[8];
    const float* g1         = (const float*)d_in[9];
    const float* b1         = (const float*)d_in[10];
    const float* g2         = (const float*)d_in[11];
    const float* b2         = (const float*)d_in[12];
    const float* W_fc1      = (const float*)d_in[13];
    const float* b_fc1      = (const float*)d_in[14];
    const float* g3         = (const float*)d_in[15];
    const float* b3         = (const float*)d_in[16];
    const float* W_fc2      = (const float*)d_in[17];
    const float* b_fc2      = (const float*)d_in[18];

    // workspace layout (4B elements)
    int*   wsi      = (int*)d_ws;
    float* wsf      = (float*)d_ws;
    int*   gbcnt    = wsi + 0;        // 784
    float* stats    = wsf + 784;      // 512
    float* pooled   = wsf + 1296;     // 4096
    int*   bbase    = wsi + 5392;     // 800 (NB+1)
    int*   gcursor  = wsi + 6192;     // 784
    int*   gstart   = wsi + 6976;     // 128
    int*   rowstart = wsi + 7104;     // 100064
    int*   pk       = wsi + 107168;   // 1600000
    int*   srcs     = wsi + 1707168;  // 1600000
    float* agg1     = wsf + 3307168;  // 300032
    unsigned short* u1b = (unsigned short*)(wsf + 3607200);   // 6.4M bf16 = 3200000 f
    unsigned short* tb  = (unsigned short*)(wsf + 6807200);   // 3200000 f
    unsigned short* pb  = (unsigned short*)(wsf + 10007200);  // 3200000 f
    unsigned short* wrelp  = (unsigned short*)(wsf + 13207200); // 4096 us = 2048 f
    unsigned short* wrootp = (unsigned short*)(wsf + 13209248); // 2048 f
    float* crel     = wsf + 13211296; // 64
    float* croot    = wsf + 13211360; // 64
    float* z        = wsf + 13211424; // 16384

    float* sums1  = stats + 0;
    float* sumsq1 = stats + 64;
    float* sums2  = stats + 128;
    float* sumsq2 = stats + 192;
    float* scale1 = stats + 256;
    float* shift1 = stats + 320;
    float* scale2 = stats + 384;
    float* shift2 = stats + 448;

    // zero gbcnt | stats | pooled (contiguous prefix, 21.6 KB)
    hipMemsetAsync(d_ws, 0, (size_t)(784 + 512 + 4096) * 4, stream);

    // CSR build: bucket-group, then per-bucket fine sort fused with x-gather
    const int EB = (E + 4095) / 4096;  // 391
    bhist_kernel<<<EB, 256, 0, stream>>>(edges, gbcnt, E);
    bscan_kernel<<<1, 256, 0, stream>>>(gbcnt, bbase, gcursor, E);
    bfill_kernel<<<EB, 256, 0, stream>>>(edges, gcursor, pk, E);
    bsort_kernel<<<NB, 256, 0, stream>>>(pk, bbase, x, rowstart, srcs, agg1, N, E);
    bounds_kernel<<<(N + 256) / 256, 256, 0, stream>>>(membership, gstart, N);

    // layer 1 dense + BN1
    layer1_kernel<<<(N + 127) / 128, 256, 0, stream>>>(
        x, agg1, W_rel1, b_rel1, W_root1, u1b, sums1, sumsq1, N);
    bnscale_kernel<<<1, 64, 0, stream>>>(sums1, sumsq1, g1, b1, 1.0f / N, 64, scale1, shift1);

    // fold BN1 into layer-2 weights, then MFMA transform
    bnfold_kernel<<<1, 256, 0, stream>>>(scale1, shift1, W_rel2, W_root2, b_rel2,
                                         wrelp, wrootp, crel, croot);
    mfma_transform_kernel<<<512, 256, 0, stream>>>(
        u1b, wrelp, wrootp, crel, croot, tb, pb, N / 16);

    // streaming bf16 gather + pool
    {
        const int GRID2 = 2048;
        int chunk = (N + GRID2 * 4 - 1) / (GRID2 * 4);  // 13
        gatherpool_kernel<<<GRID2, 256, 0, stream>>>(
            (const bf16*)tb, (const bf16*)pb, rowstart, srcs, membership,
            pooled, sums2, sumsq2, N, chunk);
    }
    bnscale_kernel<<<1, 64, 0, stream>>>(sums2, sumsq2, g2, b2, 1.0f / N, 64, scale2, shift2);

    // head
    fc1_kernel<<<1, 1024, 0, stream>>>(pooled, gstart, scale2, shift2,
                                       W_fc1, b_fc1, g3, b3, z);
    fc2_kernel<<<1, 640, 0, stream>>>(z, W_fc2, b_fc2, (float*)d_out);
}